// Round 5
// baseline (656.593 us; speedup 1.0000x reference)
//
#include <hip/hip_runtime.h>
#include <stdint.h>

// GatedLinearAttention on MI355X (gfx950)
// B=4 L=2048 HIDDEN=1024 NH=4 HDK=256 HDV=512 CHUNK=64 NCHUNK=32
// bf16 MFMA (16x16x32) for GEMM-shaped work; fp32 for gates/cumsum/log_sigmoid.

typedef float f32x4 __attribute__((ext_vector_type(4)));
typedef short s16x8 __attribute__((ext_vector_type(8)));
typedef short s16x4 __attribute__((ext_vector_type(4)));

#define DEVINL __device__ __forceinline__

DEVINL short f2bf(float f) {
  union { float f; uint32_t u; } v; v.f = f;
  uint32_t r = v.u + 0x7fffu + ((v.u >> 16) & 1u);
  return (short)(r >> 16);
}
DEVINL float bf2f(short s) {
  union { uint32_t u; float f; } v; v.u = ((uint32_t)(uint16_t)s) << 16;
  return v.f;
}
DEVINL f32x4 mfma16(s16x8 a, s16x8 b, f32x4 c) {
  return __builtin_amdgcn_mfma_f32_16x16x32_bf16(a, b, c, 0, 0, 0);
}
#define ASYNC_COPY16(G, L)                                                   \
  __builtin_amdgcn_global_load_lds(                                          \
      (__attribute__((address_space(1))) void*)(void*)(G),                   \
      (__attribute__((address_space(3))) void*)(L), 16, 0, 0)

// ---------------------------------------------------------------------------
__global__ __launch_bounds__(256) void cvt_f2b_vec(const float* __restrict__ src,
                                                   short* __restrict__ dst) {
  int id = blockIdx.x * 256 + threadIdx.x;
  f32x4 v = ((const f32x4*)src)[id];
  s16x4 o = { f2bf(v[0]), f2bf(v[1]), f2bf(v[2]), f2bf(v[3]) };
  ((s16x4*)dst)[id] = o;
}

__global__ __launch_bounds__(256) void transpose_weights(
    const float* __restrict__ Wq, const float* __restrict__ Wk,
    const float* __restrict__ Wv, const float* __restrict__ Wg,
    const float* __restrict__ Wo, short* __restrict__ wT,
    short* __restrict__ woT) {
  __shared__ short sh[64 * 66];
  const float* src; short* dst; int K, N;
  switch (blockIdx.z) {
    case 0: src = Wq; dst = wT;                         K = 1024; N = 1024; break;
    case 1: src = Wk; dst = wT + (size_t)1024 * 1024;   K = 1024; N = 1024; break;
    case 2: src = Wv; dst = wT + (size_t)2048 * 1024;   K = 1024; N = 2048; break;
    case 3: src = Wg; dst = wT + (size_t)4096 * 1024;   K = 1024; N = 2048; break;
    default: src = Wo; dst = woT;                       K = 2048; N = 1024; break;
  }
  int n0 = blockIdx.x * 64, k0 = blockIdx.y * 64;
  if (n0 >= N || k0 >= K) return;
  int tx = threadIdx.x & 63, ty = threadIdx.x >> 6;
#pragma unroll
  for (int j = 0; j < 16; j++) {
    int r = j * 4 + ty;
    sh[r * 66 + tx] = f2bf(src[(size_t)(k0 + r) * N + n0 + tx]);
  }
  __syncthreads();
#pragma unroll
  for (int j = 0; j < 16; j++) {
    int r = j * 4 + ty;
    dst[(size_t)(n0 + r) * K + k0 + tx] = sh[tx * 66 + r];
  }
}

__global__ __launch_bounds__(256) void transpose_s16_batched(const short* __restrict__ src,
                                                             short* __restrict__ dst,
                                                             int K, int N) {
  __shared__ short sh[64 * 66];
  size_t boff = (size_t)blockIdx.z * K * N;
  int n0 = blockIdx.x * 64, k0 = blockIdx.y * 64;
  int tx = threadIdx.x & 63, ty = threadIdx.x >> 6;
#pragma unroll
  for (int j = 0; j < 16; j++) {
    int r = j * 4 + ty;
    sh[r * 66 + tx] = src[boff + (size_t)(k0 + r) * N + n0 + tx];
  }
  __syncthreads();
#pragma unroll
  for (int j = 0; j < 16; j++) {
    int r = j * 4 + ty;
    dst[boff + (size_t)(n0 + r) * K + k0 + tx] = sh[tx * 66 + r];
  }
}

// ---------------------------------------------------------------------------
__global__ __launch_bounds__(256) void gk_fused(const float* __restrict__ h,
                                                const float* __restrict__ W1,
                                                const float* __restrict__ W2,
                                                const float* __restrict__ b2,
                                                float* __restrict__ gk) {
  __shared__ float pbuf[32][8][16];
  __shared__ float hl[32][16];
  const int tid = threadIdx.x;
  const int tok0 = blockIdx.x * 32;
  {
    const int tok = tid >> 3, kg = tid & 7;
    const float* hrow = h + (size_t)(tok0 + tok) * 1024 + kg * 128;
    float p[16];
#pragma unroll
    for (int c = 0; c < 16; c++) p[c] = 0.f;
    for (int i = 0; i < 128; i++) {
      float hv = hrow[i];
      const float* wrow = W1 + (size_t)(kg * 128 + i) * 16;
#pragma unroll
      for (int c = 0; c < 16; c++) p[c] += hv * wrow[c];
    }
#pragma unroll
    for (int c = 0; c < 16; c++) pbuf[tok][kg][c] = p[c];
  }
  __syncthreads();
  for (int o = tid; o < 512; o += 256) {
    int tok = o >> 4, c = o & 15;
    float s = 0.f;
#pragma unroll
    for (int g = 0; g < 8; g++) s += pbuf[tok][g][c];
    hl[tok][c] = s;
  }
  __syncthreads();
#pragma unroll
  for (int j = 0; j < 4; j++) {
    int n = j * 256 + tid;
    float w[16];
#pragma unroll
    for (int c = 0; c < 16; c++) w[c] = W2[c * 1024 + n];
    float bias = b2[n];
    for (int t = 0; t < 32; t++) {
      float raw = bias;
#pragma unroll
      for (int c = 0; c < 16; c++) raw += hl[t][c] * w[c];
      float ls = fminf(raw, 0.f) - log1pf(__expf(-fabsf(raw)));
      gk[(size_t)(tok0 + t) * 1024 + n] = ls * 0.0625f;
    }
  }
}

// ---------------------------------------------------------------------------
// bf16 GEMM, 128x128 tile, BK=64, global_load_lds staging, T2 swizzle.
// XCD-aware 2D supertiling (MODE0: grid 64x48 fixed; MODE1: 64x8 fixed):
// each XCD gets a 2D rect walked in 8x8 subtiles (A 2MB + B 2MB ~ L2-resident).
template <int MODE>
__global__ __launch_bounds__(256) void gemm_bf16(const short* __restrict__ A,
                                                 const short* __restrict__ Bt, int K,
                                                 short* __restrict__ oQ,
                                                 short* __restrict__ oK,
                                                 short* __restrict__ oV,
                                                 short* __restrict__ oG,
                                                 float* __restrict__ oD) {
  __shared__ short ldsA[128 * 64];
  __shared__ short ldsB[128 * 64];
  const int tid = threadIdx.x;
  const int w = tid >> 6, lane = tid & 63;
  const int wm = w >> 1, wn = w & 1;
  int bx, by;
  {
    const int orig = blockIdx.y * gridDim.x + blockIdx.x;
    const int x = orig & 7;       // presumed XCD
    const int j = orig >> 3;
    if (MODE == 0) {  // grid 64x48: XCD rect 16x24, 8x8 subtiles (2x3)
      const int rx = x & 3, ry = x >> 2;
      const int sub = j >> 6, t = j & 63;
      const int sx = sub & 1, sy = sub >> 1;
      bx = rx * 16 + sx * 8 + (t & 7);
      by = ry * 24 + sy * 8 + (t >> 3);
    } else {          // grid 64x8: XCD rect bx in [8x,8x+8) x all by
      bx = x * 8 + (j & 7);
      by = j >> 3;
    }
  }
  const int rowA0 = bx * 128, rowB0 = by * 128;
  f32x4 acc[4][4];
#pragma unroll
  for (int m = 0; m < 4; m++)
#pragma unroll
    for (int n = 0; n < 4; n++) acc[m][n] = (f32x4){0.f, 0.f, 0.f, 0.f};

  for (int kt = 0; kt < K; kt += 64) {
#pragma unroll
    for (int i = 0; i < 4; i++) {
      int X = i * 4096 + tid * 16;
      int r = X >> 7;
      int cB = (X & 127) ^ ((r & 7) << 4);
      ASYNC_COPY16((const char*)A + ((size_t)(rowA0 + r) * K + kt) * 2 + cB,
                   (char*)ldsA + X);
      ASYNC_COPY16((const char*)Bt + ((size_t)(rowB0 + r) * K + kt) * 2 + cB,
                   (char*)ldsB + X);
    }
    __syncthreads();
#pragma unroll
    for (int kk = 0; kk < 2; kk++) {
      s16x8 af[4], bfv[4];
#pragma unroll
      for (int mt = 0; mt < 4; mt++) {
        int row = wm * 64 + mt * 16 + (lane & 15);
        int lin = row * 128 + (kk * 32 + 8 * (lane >> 4)) * 2;
        af[mt] = *(const s16x8*)((const char*)ldsA + (lin ^ ((row & 7) << 4)));
      }
#pragma unroll
      for (int nt = 0; nt < 4; nt++) {
        int rowb = wn * 64 + nt * 16 + (lane & 15);
        int lin = rowb * 128 + (kk * 32 + 8 * (lane >> 4)) * 2;
        bfv[nt] = *(const s16x8*)((const char*)ldsB + (lin ^ ((rowb & 7) << 4)));
      }
#pragma unroll
      for (int mt = 0; mt < 4; mt++)
#pragma unroll
        for (int nt = 0; nt < 4; nt++) acc[mt][nt] = mfma16(af[mt], bfv[nt], acc[mt][nt]);
    }
    __syncthreads();
  }
#pragma unroll
  for (int mt = 0; mt < 4; mt++) {
#pragma unroll
    for (int nt = 0; nt < 4; nt++) {
      int grow0 = rowA0 + wm * 64 + mt * 16 + 4 * (lane >> 4);
      int gcol = rowB0 + wn * 64 + nt * 16 + (lane & 15);
#pragma unroll
      for (int r = 0; r < 4; r++) {
        int grow = grow0 + r;
        float val = acc[mt][nt][r];
        if (MODE == 0) {
          int sec = gcol >> 10;
          if (sec == 0)      oQ[(size_t)grow * 1024 + gcol] = f2bf(val);
          else if (sec == 1) oK[(size_t)grow * 1024 + (gcol - 1024)] = f2bf(val);
          else if (sec < 4)  oV[(size_t)grow * 2048 + (gcol - 2048)] = f2bf(val);
          else               oG[(size_t)grow * 2048 + (gcol - 4096)] = f2bf(val);
        } else {
          oD[(size_t)grow * 1024 + gcol] = val;
        }
      }
    }
  }
}

// ---------------------------------------------------------------------------
// intra: per-(chunk, bh). 4 waves. Outputs qg, ksT, Adec, o_intra (LDS-staged
// coalesced flush). LDS: 64KB union (qg/ki then o-stage) + 8KB score + 1KB.
__global__ __launch_bounds__(256) void gla_intra(const short* __restrict__ Qb,
                                                 const short* __restrict__ Kb,
                                                 const float* __restrict__ gkp,
                                                 const short* __restrict__ VbT,
                                                 short* __restrict__ qg_g,
                                                 short* __restrict__ ksT_g,
                                                 float* __restrict__ Adec,
                                                 short* __restrict__ obA) {
  __shared__ short smem[64 * 512];     // qgbuf[64*256] | kibuf[64*256]; later o-stage
  __shared__ short scorebuf[64 * 64];
  __shared__ float adecs[256];
  short* qgbuf = smem;
  short* kibuf = smem + 64 * 256;

  const int ch = blockIdx.x, bh = blockIdx.y;
  const int b = bh >> 2, h = bh & 3;
  const int tok0 = b * 2048 + ch * 64;
  const int ltk0 = ch * 64;
  const int tid = threadIdx.x;
  const int col = h * 256 + tid;

  // phase 1: cumsum + gated q/k
  const float scale_ = 0.0625f;
  float cs = 0.f;
#pragma unroll 4
  for (int t = 0; t < 64; t++) {
    size_t ri = (size_t)(tok0 + t) * 1024 + col;
    cs += gkp[ri];
    float qv = bf2f(Qb[ri]);
    float kv = bf2f(Kb[ri]);
    float ep = __expf(cs);
    float en = __expf(-cs);
    short qb = f2bf(qv * ep * scale_);
    short kb = f2bf(kv * en);
    int lin = t * 512 + tid * 2;
    int sw = (t & 7) << 4;
    *(short*)((char*)qgbuf + (lin ^ sw)) = qb;
    *(short*)((char*)kibuf + (lin ^ sw)) = kb;
    qg_g[ri] = qb;
  }
  float elast = __expf(cs);
  Adec[(bh * 32 + ch) * 256 + tid] = elast;
  adecs[tid] = elast;
  __syncthreads();

  // phase 2: scores = q_g @ k_intra^T (tril-masked) -> scorebuf
  const int w = tid >> 6, lane = tid & 63;
  {
    f32x4 sc[4];
#pragma unroll
    for (int nt = 0; nt < 4; nt++) sc[nt] = (f32x4){0.f, 0.f, 0.f, 0.f};
#pragma unroll
    for (int kk = 0; kk < 8; kk++) {
      int row = 16 * w + (lane & 15);
      int lin = row * 512 + (kk * 32 + 8 * (lane >> 4)) * 2;
      s16x8 a = *(const s16x8*)((const char*)qgbuf + (lin ^ ((row & 7) << 4)));
#pragma unroll
      for (int nt = 0; nt < 4; nt++) {
        int tj = nt * 16 + (lane & 15);
        int linb = tj * 512 + (kk * 32 + 8 * (lane >> 4)) * 2;
        s16x8 bb = *(const s16x8*)((const char*)kibuf + (linb ^ ((tj & 7) << 4)));
        sc[nt] = mfma16(a, bb, sc[nt]);
      }
    }
#pragma unroll
    for (int nt = 0; nt < 4; nt++) {
#pragma unroll
      for (int r = 0; r < 4; r++) {
        int ri = 16 * w + 4 * (lane >> 4) + r;
        int cj = nt * 16 + (lane & 15);
        float v = (cj <= ri) ? sc[nt][r] : 0.f;
        int lin = ri * 128 + cj * 2;
        *(short*)((char*)scorebuf + (lin ^ ((ri & 7) << 4))) = f2bf(v);
      }
    }
  }
  __syncthreads();

  // phase 2.5: k_state^T = kibuf^T * elast -> global
  size_t ksb = (size_t)(bh * 32 + ch) * 16384;
#pragma unroll
  for (int j = 0; j < 8; j++) {
    int E = j * 2048 + tid * 8;
    int d = E >> 6, t0 = E & 63;
    float el = adecs[d];
    s16x8 v;
#pragma unroll
    for (int r = 0; r < 8; r++) {
      int t = t0 + r;
      short ki = *(const short*)((const char*)kibuf + ((t * 512 + d * 2) ^ ((t & 7) << 4)));
      v[r] = f2bf(bf2f(ki) * el);
    }
    *(s16x8*)(ksT_g + ksb + E) = v;
  }
  __syncthreads();  // kibuf/qgbuf now dead -> smem becomes o-stage [64][512]

  // phase 3: o_intra = scores @ v -> o-stage (then coalesced flush)
  {
    s16x8 a2[2];
#pragma unroll
    for (int kk = 0; kk < 2; kk++) {
      int row = 16 * w + (lane & 15);
      int lin = row * 128 + (kk * 32 + 8 * (lane >> 4)) * 2;
      a2[kk] = *(const s16x8*)((const char*)scorebuf + (lin ^ ((row & 7) << 4)));
    }
    for (int nt = 0; nt < 32; nt++) {
      int e = nt * 16 + (lane & 15);
      f32x4 oacc = (f32x4){0.f, 0.f, 0.f, 0.f};
#pragma unroll
      for (int kk = 0; kk < 2; kk++) {
        const s16x8 bb = *(const s16x8*)(VbT + ((size_t)bh * 512 + e) * 2048 + ltk0 + kk * 32 + 8 * (lane >> 4));
        oacc = mfma16(a2[kk], bb, oacc);
      }
#pragma unroll
      for (int r = 0; r < 4; r++) {
        int ri = 16 * w + 4 * (lane >> 4) + r;
        int lin3 = ri * 1024 + e * 2;
        *(short*)((char*)smem + (lin3 ^ ((ri & 7) << 4))) = f2bf(oacc[r]);
      }
    }
  }
  __syncthreads();
  // flush: 64 rows x 512 cols bf16, 16B/lane coalesced
#pragma unroll
  for (int it = 0; it < 16; it++) {
    int row = it * 4 + (tid >> 6);
    int vec = tid & 63;
    int lin = row * 1024 + vec * 16;
    s16x8 v = *(const s16x8*)((const char*)smem + (lin ^ ((row & 7) << 4)));
    *(s16x8*)(obA + (size_t)(tok0 + row) * 2048 + h * 512 + vec * 8) = v;
  }
}

// ---------------------------------------------------------------------------
// state pass: sequential chunks 0..23, materialize boundary states S_8,S_16,S_24
// (bf16 S^T slices) for the 4-way-parallel scan. Grid (seg 16, bh 16), 4 waves.
// Wave w: dk 64w..+63 x block dv 32. No barriers except at the 3 flushes.
__global__ __launch_bounds__(256) void gla_state(const short* __restrict__ ksT_g,
                                                 const short* __restrict__ VbT,
                                                 const float* __restrict__ Adec,
                                                 short* __restrict__ Sb) {
  __shared__ short st[32 * 256];  // 16KB flush staging
  const int seg = blockIdx.x, bh = blockIdx.y;
  const int tid = threadIdx.x;
  const int w = tid >> 6, lane = tid & 63;

  f32x4 S[4][2];
#pragma unroll
  for (int mt = 0; mt < 4; mt++)
#pragma unroll
    for (int nt = 0; nt < 2; nt++) S[mt][nt] = (f32x4){0.f, 0.f, 0.f, 0.f};

  for (int ch = 0; ch < 24; ch++) {
    const int ltk0 = ch * 64;
    // decay
#pragma unroll
    for (int mt = 0; mt < 4; mt++) {
      int dkb = 64 * w + mt * 16 + 4 * (lane >> 4);
      f32x4 a = *(const f32x4*)(Adec + (size_t)(bh * 32 + ch) * 256 + dkb);
#pragma unroll
      for (int nt = 0; nt < 2; nt++) {
        S[mt][nt][0] *= a[0]; S[mt][nt][1] *= a[1];
        S[mt][nt][2] *= a[2]; S[mt][nt][3] *= a[3];
      }
    }
    // update S += ks^T @ v
    size_t ksb = (size_t)(bh * 32 + ch) * 16384;
#pragma unroll
    for (int kk = 0; kk < 2; kk++) {
      s16x8 ak[4];
#pragma unroll
      for (int mt = 0; mt < 4; mt++) {
        int dk = 64 * w + mt * 16 + (lane & 15);
        ak[mt] = *(const s16x8*)(ksT_g + ksb + (size_t)dk * 64 + kk * 32 + 8 * (lane >> 4));
      }
#pragma unroll
      for (int nt = 0; nt < 2; nt++) {
        int e = seg * 32 + nt * 16 + (lane & 15);
        s16x8 bv = *(const s16x8*)(VbT + ((size_t)bh * 512 + e) * 2048 + ltk0 + kk * 32 + 8 * (lane >> 4));
#pragma unroll
        for (int mt = 0; mt < 4; mt++) S[mt][nt] = mfma16(ak[mt], bv, S[mt][nt]);
      }
    }
    // boundary flush: S^T (bf16) -> Sb[g][bh][dv 512][dk 256]
    if (ch == 7 || ch == 15 || ch == 23) {
      int g = (ch - 7) >> 3;
      __syncthreads();  // st reusable (prev flush reads done)
#pragma unroll
      for (int mt = 0; mt < 4; mt++) {
#pragma unroll
        for (int nt = 0; nt < 2; nt++) {
          int dv = nt * 16 + (lane & 15);
          int dk0 = 64 * w + mt * 16 + 4 * (lane >> 4);
          s16x4 pk = { f2bf(S[mt][nt][0]), f2bf(S[mt][nt][1]), f2bf(S[mt][nt][2]), f2bf(S[mt][nt][3]) };
          int lin = dv * 512 + dk0 * 2;
          *(s16x4*)((char*)st + (lin ^ ((dv & 7) << 4))) = pk;
        }
      }
      __syncthreads();
      char* dstb = (char*)Sb + (((size_t)(g * 16 + bh) * 512 + seg * 32) * 256) * 2;
#pragma unroll
      for (int it = 0; it < 4; it++) {
        int dv = it * 8 + (tid >> 5);
        int vec = tid & 31;
        int X = dv * 512 + vec * 16;
        s16x8 v = *(const s16x8*)((const char*)st + (X ^ ((dv & 7) << 4)));
        *(s16x8*)(dstb + X) = v;
      }
    }
  }
}

// ---------------------------------------------------------------------------
// scan: 4-way parallel over chunk groups. Grid (seg 16, bh 16, g 4), 8 waves.
// Wave w: S rows 32w..+31 (dk) x block's 32 dv, fp32. g>0 starts from Sb[g-1].
__global__ __launch_bounds__(512) void gla_scan(const short* __restrict__ qg_g,
                                                const short* __restrict__ ksT_g,
                                                const short* __restrict__ VbT,
                                                const float* __restrict__ Adec,
                                                const short* __restrict__ Sb,
                                                short* __restrict__ obB) {
  __shared__ short st[32 * 256];  // S^T [dv 32][dk 256] bf16, swizzled
  const int seg = blockIdx.x, bh = blockIdx.y, gz = blockIdx.z;
  const int b = bh >> 2, h = bh & 3;
  const int tid = threadIdx.x;
  const int w = tid >> 6, lane = tid & 63;
  const int tt = w & 3;
  const int dh = w >> 2;
  const int ch0 = gz * 8;

  f32x4 S[2][2];
#pragma unroll
  for (int mt = 0; mt < 2; mt++)
#pragma unroll
    for (int nt = 0; nt < 2; nt++) S[mt][nt] = (f32x4){0.f, 0.f, 0.f, 0.f};

  if (gz > 0) {
    // stage Sb[gz-1] slice -> st (coalesced, swizzled on LDS write)
    const char* srcb = (const char*)Sb + ((((size_t)(gz - 1) * 16 + bh) * 512 + seg * 32) * 256) * 2;
#pragma unroll
    for (int it = 0; it < 2; it++) {
      int dv = it * 16 + (tid >> 5);
      int vec = tid & 31;
      int X = dv * 512 + vec * 16;
      s16x8 v = *(const s16x8*)(srcb + X);
      *(s16x8*)((char*)st + (X ^ ((dv & 7) << 4))) = v;
    }
    __syncthreads();
    // init S regs from st
#pragma unroll
    for (int mt = 0; mt < 2; mt++) {
#pragma unroll
      for (int nt = 0; nt < 2; nt++) {
        int dv = nt * 16 + (lane & 15);
        int dk0 = 32 * w + mt * 16 + 4 * (lane >> 4);
        int lin = dv * 512 + dk0 * 2;
        s16x4 pk = *(const s16x4*)((const char*)st + (lin ^ ((dv & 7) << 4)));
        S[mt][nt][0] = bf2f(pk[0]); S[mt][nt][1] = bf2f(pk[1]);
        S[mt][nt][2] = bf2f(pk[2]); S[mt][nt][3] = bf2f(pk[3]);
      }
    }
  }

  for (int ch = ch0; ch < ch0 + 8; ch++) {
    const int tok0 = b * 2048 + ch * 64;
    const int ltk0 = ch * 64;

    // 1. S -> S^T in LDS (skip on first iter of g>0: st already staged)
    if (ch != ch0 || gz == 0) {
#pragma unroll
      for (int mt = 0; mt < 2; mt++) {
#pragma unroll
        for (int nt = 0; nt < 2; nt++) {
          int dv = nt * 16 + (lane & 15);
          int dk0 = 32 * w + mt * 16 + 4 * (lane >> 4);
          s16x4 pk = { f2bf(S[mt][nt][0]), f2bf(S[mt][nt][1]), f2bf(S[mt][nt][2]), f2bf(S[mt][nt][3]) };
          int lin = dv * 512 + dk0 * 2;
          *(s16x4*)((char*)st + (lin ^ ((dv & 7) << 4))) = pk;
        }
      }
    }
    __syncthreads();

    // 2. o_inter = q_g @ S_old (one 16x16 tile per wave, split acc for ILP)
    {
      s16x8 aq[8];
#pragma unroll
      for (int kk = 0; kk < 8; kk++) {
        int ti = tok0 + 16 * tt + (lane & 15);
        aq[kk] = *(const s16x8*)(qg_g + (size_t)ti * 1024 + h * 256 + kk * 32 + 8 * (lane >> 4));
      }
      f32x4 oi0 = (f32x4){0.f, 0.f, 0.f, 0.f};
      f32x4 oi1 = (f32x4){0.f, 0.f, 0.f, 0.f};
      int dv = 16 * dh + (lane & 15);
      __builtin_amdgcn_s_setprio(1);
#pragma unroll
      for (int kk = 0; kk < 8; kk += 2) {
        int lin0 = dv * 512 + (kk * 32 + 8 * (lane >> 4)) * 2;
        int lin1 = dv * 512 + ((kk + 1) * 32 + 8 * (lane >> 4)) * 2;
        s16x8 b0 = *(const s16x8*)((const char*)st + (lin0 ^ ((dv & 7) << 4)));
        s16x8 b1 = *(const s16x8*)((const char*)st + (lin1 ^ ((dv & 7) << 4)));
        oi0 = mfma16(aq[kk], b0, oi0);
        oi1 = mfma16(aq[kk + 1], b1, oi1);
      }
      __builtin_amdgcn_s_setprio(0);
#pragma unroll
      for (int r = 0; r < 4; r++) {
        int ti = tok0 + 16 * tt + 4 * (lane >> 4) + r;
        obB[(size_t)ti * 2048 + h * 512 + seg * 32 + 16 * dh + (lane & 15)] =
            f2bf(oi0[r] + oi1[r]);
      }
    }

    // 3. decay
#pragma unroll
    for (int mt = 0; mt < 2; mt++) {
      int dkb = 32 * w + mt * 16 + 4 * (lane >> 4);
      f32x4 a = *(const f32x4*)(Adec + (size_t)(bh * 32 + ch) * 256 + dkb);
#pragma unroll
      for (int nt = 0; nt < 2; nt++) {
        S[mt][nt][0] *= a[0]; S[mt][nt][1] *= a[1];
        S[mt][nt][2] *= a[2]; S[mt][nt][3] *= a[3];
      }
    }

    // 4. update: S += ks^T @ v
    size_t ksb = (size_t)(bh * 32 + ch) * 16384;
#pragma unroll
    for (int kk = 0; kk < 2; kk++) {
      s16x8 ak[2];
#pragma unroll
      for (int mt = 0; mt < 2; mt++) {
        int dk = 32 * w + mt * 16 + (lane & 15);
        ak[mt] = *(const s16x8*)(ksT_g + ksb + (size_t)dk * 64 + kk * 32 + 8 * (lane >> 4));
      }
#pragma unroll
      for (int nt = 0; nt < 2; nt++) {
        int e = seg * 32 + nt * 16 + (lane & 15);
        s16x8 bv = *(const s16x8*)(VbT + ((size_t)bh * 512 + e) * 2048 + ltk0 + kk * 32 + 8 * (lane >> 4));
#pragma unroll
        for (int mt = 0; mt < 2; mt++) S[mt][nt] = mfma16(ak[mt], bv, S[mt][nt]);
      }
    }
    __syncthreads();
  }
}

// ---------------------------------------------------------------------------
__global__ __launch_bounds__(256) void gate_norm(const short* __restrict__ obA,
                                                 const short* __restrict__ obB,
                                                 const short* __restrict__ Gb,
                                                 const float* __restrict__ gnw,
                                                 short* __restrict__ gated) {
  int row = blockIdx.x, tid = threadIdx.x;
  int lane = tid & 63;
  size_t base = (size_t)row * 2048 + (tid >> 6) * 512 + lane * 8;
  s16x8 av = *(const s16x8*)(obA + base);
  s16x8 bv = *(const s16x8*)(obB + base);
  s16x8 gv = *(const s16x8*)(Gb + base);
  float o[8];
  float ss = 0.f;
#pragma unroll
  for (int j = 0; j < 8; j++) {
    o[j] = bf2f(av[j]) + bf2f(bv[j]);
    ss += o[j] * o[j];
  }
#pragma unroll
  for (int off = 32; off > 0; off >>= 1) ss += __shfl_xor(ss, off);
  float rinv = rsqrtf(ss * (1.0f / 512.0f) + 1e-5f);
  f32x4 w0 = *(const f32x4*)(gnw + lane * 8);
  f32x4 w1 = *(const f32x4*)(gnw + lane * 8 + 4);
  s16x8 out;
#pragma unroll
  for (int j = 0; j < 8; j++) {
    float g = bf2f(gv[j]);
    float sg = g / (1.f + __expf(-g));
    float wj = (j < 4) ? w0[j] : w1[j - 4];
    out[j] = f2bf(o[j] * rinv * wj * sg);
  }
  *(s16x8*)(gated + base) = out;
}

// ---------------------------------------------------------------------------
extern "C" void kernel_launch(void* const* d_in, const int* in_sizes, int n_in,
                              void* d_out, int out_size, void* d_ws, size_t ws_size,
                              hipStream_t stream) {
  const float* hsrc = (const float*)d_in[0];
  const float* Wq   = (const float*)d_in[1];
  const float* Wk   = (const float*)d_in[2];
  const float* Wv   = (const float*)d_in[3];
  const float* Wg   = (const float*)d_in[4];
  const float* Wgk1 = (const float*)d_in[5];
  const float* Wgk2 = (const float*)d_in[6];
  const float* bgk2 = (const float*)d_in[7];
  const float* gnw  = (const float*)d_in[8];
  const float* Wo   = (const float*)d_in[9];
  float* out = (float*)d_out;

  // workspace layout (~265 MB), all 16B-aligned
  short* hbf = (short*)d_ws;                     // 8192x1024
  short* wT  = hbf + (size_t)8192 * 1024;        // 6144x1024 (Wq|Wk|Wv|Wg)^T
  short* woT = wT + (size_t)6144 * 1024;         // 1024x2048 Wo^T
  short* Qb  = woT + (size_t)1024 * 2048;        // 8192x1024
  short* Kb  = Qb + (size_t)8192 * 1024;
  short* Vb  = Kb + (size_t)8192 * 1024;         // 8192x2048
  short* Gb  = Vb + (size_t)8192 * 2048;         // 8192x2048
  short* VbT = Gb + (size_t)8192 * 2048;         // per-batch V^T
  short* ksT = VbT + (size_t)8192 * 2048;        // [bh*32+ch][256][64]
  short* obA = ksT + (size_t)16 * 32 * 256 * 64; // 8192x2048 o_intra
  float* gkb = (float*)(obA + (size_t)8192 * 2048); // 8192x1024 f32
  float* Adec = gkb + (size_t)8192 * 1024;       // 16*32*256 f32
  short* Sb  = (short*)(Adec + (size_t)16 * 32 * 256); // 3x16x512x256 bf16 (12.6MB)
  short* qg    = hbf;           // alias: hbf dead after QKVG GEMM
  short* gated = Vb;            // alias: Vb dead after V transpose
  short* obB   = (short*)d_out; // alias: consumed before final GEMM writes

  cvt_f2b_vec<<<8192, 256, 0, stream>>>(hsrc, hbf);
  transpose_weights<<<dim3(32, 32, 5), 256, 0, stream>>>(Wq, Wk, Wv, Wg, Wo, wT, woT);
  gk_fused<<<256, 256, 0, stream>>>(hsrc, Wgk1, Wgk2, bgk2, gkb);
  gemm_bf16<0><<<dim3(64, 48), 256, 0, stream>>>(hbf, wT, 1024, Qb, Kb, Vb, Gb, nullptr);
  transpose_s16_batched<<<dim3(32, 32, 4), 256, 0, stream>>>(Vb, VbT, 2048, 2048);
  gla_intra<<<dim3(32, 16), 256, 0, stream>>>(Qb, Kb, gkb, VbT, qg, ksT, Adec, obA);
  gla_state<<<dim3(16, 16), 256, 0, stream>>>(ksT, VbT, Adec, Sb);
  gla_scan<<<dim3(16, 16, 4), 512, 0, stream>>>(qg, ksT, VbT, Adec, Sb, obB);
  gate_norm<<<8192, 256, 0, stream>>>(obA, obB, Gb, gnw, gated);
  gemm_bf16<1><<<dim3(64, 8), 256, 0, stream>>>(gated, woT, 2048, nullptr, nullptr, nullptr, nullptr, out);
}

// Round 7
// 652.410 us; speedup vs baseline: 1.0064x; 1.0064x over previous
//
#include <hip/hip_runtime.h>
#include <stdint.h>

// GatedLinearAttention on MI355X (gfx950)
// B=4 L=2048 HIDDEN=1024 NH=4 HDK=256 HDV=512 CHUNK=64 NCHUNK=32
// bf16 MFMA (16x16x32) for GEMM-shaped work; fp32 for gates/cumsum/log_sigmoid.

typedef float f32x4 __attribute__((ext_vector_type(4)));
typedef short s16x8 __attribute__((ext_vector_type(8)));
typedef short s16x4 __attribute__((ext_vector_type(4)));

#define DEVINL __device__ __forceinline__

DEVINL short f2bf(float f) {
  union { float f; uint32_t u; } v; v.f = f;
  uint32_t r = v.u + 0x7fffu + ((v.u >> 16) & 1u);
  return (short)(r >> 16);
}
DEVINL float bf2f(short s) {
  union { uint32_t u; float f; } v; v.u = ((uint32_t)(uint16_t)s) << 16;
  return v.f;
}
DEVINL f32x4 mfma16(s16x8 a, s16x8 b, f32x4 c) {
  return __builtin_amdgcn_mfma_f32_16x16x32_bf16(a, b, c, 0, 0, 0);
}
#define ASYNC_COPY16(G, L)                                                   \
  __builtin_amdgcn_global_load_lds(                                          \
      (__attribute__((address_space(1))) void*)(void*)(G),                   \
      (__attribute__((address_space(3))) void*)(L), 16, 0, 0)

// ---------------------------------------------------------------------------
__global__ __launch_bounds__(256) void cvt_f2b_vec(const float* __restrict__ src,
                                                   short* __restrict__ dst) {
  int id = blockIdx.x * 256 + threadIdx.x;
  f32x4 v = ((const f32x4*)src)[id];
  s16x4 o = { f2bf(v[0]), f2bf(v[1]), f2bf(v[2]), f2bf(v[3]) };
  ((s16x4*)dst)[id] = o;
}

__global__ __launch_bounds__(256) void transpose_weights(
    const float* __restrict__ Wq, const float* __restrict__ Wk,
    const float* __restrict__ Wv, const float* __restrict__ Wg,
    const float* __restrict__ Wo, short* __restrict__ wT,
    short* __restrict__ woT) {
  __shared__ short sh[64 * 66];
  const float* src; short* dst; int K, N;
  switch (blockIdx.z) {
    case 0: src = Wq; dst = wT;                         K = 1024; N = 1024; break;
    case 1: src = Wk; dst = wT + (size_t)1024 * 1024;   K = 1024; N = 1024; break;
    case 2: src = Wv; dst = wT + (size_t)2048 * 1024;   K = 1024; N = 2048; break;
    case 3: src = Wg; dst = wT + (size_t)4096 * 1024;   K = 1024; N = 2048; break;
    default: src = Wo; dst = woT;                       K = 2048; N = 1024; break;
  }
  int n0 = blockIdx.x * 64, k0 = blockIdx.y * 64;
  if (n0 >= N || k0 >= K) return;
  int tx = threadIdx.x & 63, ty = threadIdx.x >> 6;
#pragma unroll
  for (int j = 0; j < 16; j++) {
    int r = j * 4 + ty;
    sh[r * 66 + tx] = f2bf(src[(size_t)(k0 + r) * N + n0 + tx]);
  }
  __syncthreads();
#pragma unroll
  for (int j = 0; j < 16; j++) {
    int r = j * 4 + ty;
    dst[(size_t)(n0 + r) * K + k0 + tx] = sh[tx * 66 + r];
  }
}

__global__ __launch_bounds__(256) void transpose_s16_batched(const short* __restrict__ src,
                                                             short* __restrict__ dst,
                                                             int K, int N) {
  __shared__ short sh[64 * 66];
  size_t boff = (size_t)blockIdx.z * K * N;
  int n0 = blockIdx.x * 64, k0 = blockIdx.y * 64;
  int tx = threadIdx.x & 63, ty = threadIdx.x >> 6;
#pragma unroll
  for (int j = 0; j < 16; j++) {
    int r = j * 4 + ty;
    sh[r * 66 + tx] = src[boff + (size_t)(k0 + r) * N + n0 + tx];
  }
  __syncthreads();
#pragma unroll
  for (int j = 0; j < 16; j++) {
    int r = j * 4 + ty;
    dst[boff + (size_t)(n0 + r) * K + k0 + tx] = sh[tx * 66 + r];
  }
}

// ---------------------------------------------------------------------------
__global__ __launch_bounds__(256) void gk_fused(const float* __restrict__ h,
                                                const float* __restrict__ W1,
                                                const float* __restrict__ W2,
                                                const float* __restrict__ b2,
                                                float* __restrict__ gk) {
  __shared__ float pbuf[32][8][16];
  __shared__ float hl[32][16];
  const int tid = threadIdx.x;
  const int tok0 = blockIdx.x * 32;
  {
    const int tok = tid >> 3, kg = tid & 7;
    const float* hrow = h + (size_t)(tok0 + tok) * 1024 + kg * 128;
    float p[16];
#pragma unroll
    for (int c = 0; c < 16; c++) p[c] = 0.f;
    for (int i = 0; i < 128; i++) {
      float hv = hrow[i];
      const float* wrow = W1 + (size_t)(kg * 128 + i) * 16;
#pragma unroll
      for (int c = 0; c < 16; c++) p[c] += hv * wrow[c];
    }
#pragma unroll
    for (int c = 0; c < 16; c++) pbuf[tok][kg][c] = p[c];
  }
  __syncthreads();
  for (int o = tid; o < 512; o += 256) {
    int tok = o >> 4, c = o & 15;
    float s = 0.f;
#pragma unroll
    for (int g = 0; g < 8; g++) s += pbuf[tok][g][c];
    hl[tok][c] = s;
  }
  __syncthreads();
#pragma unroll
  for (int j = 0; j < 4; j++) {
    int n = j * 256 + tid;
    float w[16];
#pragma unroll
    for (int c = 0; c < 16; c++) w[c] = W2[c * 1024 + n];
    float bias = b2[n];
    for (int t = 0; t < 32; t++) {
      float raw = bias;
#pragma unroll
      for (int c = 0; c < 16; c++) raw += hl[t][c] * w[c];
      float ls = fminf(raw, 0.f) - log1pf(__expf(-fabsf(raw)));
      gk[(size_t)(tok0 + t) * 1024 + n] = ls * 0.0625f;
    }
  }
}

// ---------------------------------------------------------------------------
// QKVG GEMM: 256x256 tile, BK=64, 8 waves (2Mx4N), double-buffered 128KB LDS,
// counted-vmcnt pipeline (T3/T4), setprio (T5), proven swizzle (r4/r5: 0 bank
// conflicts). Per wave: 128x64 output = acc[8][4]. 2 raw barriers/K-tile,
// vmcnt never drained to 0 mid-loop; tile t+2 staged after read-barrier.
__global__ __launch_bounds__(512, 2) void gemm256(const short* __restrict__ A,
                                                  const short* __restrict__ Bt, int K,
                                                  short* __restrict__ oQ,
                                                  short* __restrict__ oK,
                                                  short* __restrict__ oV,
                                                  short* __restrict__ oG) {
  __shared__ short lds[2][2][2][128 * 64];  // [buf][op A/B][half][128 rows x 64]
  const int tid = threadIdx.x;
  const int wv = tid >> 6, lane = tid & 63;
  const int wm = wv >> 2, wn = wv & 3;  // 2M x 4N wave grid
  const int rowA0 = blockIdx.x * 256, rowB0 = blockIdx.y * 256;
  const int NT = K >> 6;

  f32x4 acc[8][4];
#pragma unroll
  for (int i = 0; i < 8; i++)
#pragma unroll
    for (int j = 0; j < 4; j++) acc[i][j] = (f32x4){0.f, 0.f, 0.f, 0.f};

#define STAGE256(kt, buf)                                                          \
  do {                                                                             \
    _Pragma("unroll") for (int part = 0; part < 2; part++) {                       \
      int X = part * 8192 + tid * 16;                                              \
      int r = X >> 7;                                                              \
      int cB = (X & 127) ^ ((r & 7) << 4);                                         \
      _Pragma("unroll") for (int half = 0; half < 2; half++) {                     \
        ASYNC_COPY16((const char*)A + ((size_t)(rowA0 + half * 128 + r) * K + (kt)) * 2 + cB, \
                     (char*)&lds[buf][0][half][0] + X);                            \
        ASYNC_COPY16((const char*)Bt + ((size_t)(rowB0 + half * 128 + r) * K + (kt)) * 2 + cB, \
                     (char*)&lds[buf][1][half][0] + X);                            \
      }                                                                            \
    }                                                                              \
  } while (0)

  STAGE256(0, 0);
  if (NT > 1) STAGE256(64, 1);

  for (int t = 0; t < NT; t++) {
    const int cur = t & 1;
    // own tile-t loads (8) landed; next tile's 8 may stay in flight (T4)
    if (t + 1 < NT) asm volatile("s_waitcnt vmcnt(8)" ::: "memory");
    else            asm volatile("s_waitcnt vmcnt(0)" ::: "memory");
    __builtin_amdgcn_s_barrier();
    __builtin_amdgcn_sched_barrier(0);
#pragma unroll
    for (int kk = 0; kk < 2; kk++) {
      s16x8 af[8];
#pragma unroll
      for (int rt = 0; rt < 8; rt++) {
        int lr = rt * 16 + (lane & 15);
        int lin = lr * 128 + (kk * 32 + 8 * (lane >> 4)) * 2;
        af[rt] = *(const s16x8*)((const char*)&lds[cur][0][wm][0] + (lin ^ ((lr & 7) << 4)));
      }
#pragma unroll
      for (int ch = 0; ch < 2; ch++) {
        s16x8 bf[2];
#pragma unroll
        for (int ct = 0; ct < 2; ct++) {
          int col = wn * 64 + ch * 32 + ct * 16 + (lane & 15);
          int bh = col >> 7, lc = col & 127;
          int lin = lc * 128 + (kk * 32 + 8 * (lane >> 4)) * 2;
          bf[ct] = *(const s16x8*)((const char*)&lds[cur][1][bh][0] + (lin ^ ((lc & 7) << 4)));
        }
        __builtin_amdgcn_s_setprio(1);
#pragma unroll
        for (int rt = 0; rt < 8; rt++) {
          acc[rt][ch * 2 + 0] = mfma16(af[rt], bf[0], acc[rt][ch * 2 + 0]);
          acc[rt][ch * 2 + 1] = mfma16(af[rt], bf[1], acc[rt][ch * 2 + 1]);
        }
        __builtin_amdgcn_s_setprio(0);
      }
    }
    __builtin_amdgcn_sched_barrier(0);
    __builtin_amdgcn_s_barrier();  // all waves done reading buf[cur]
    if (t + 2 < NT) STAGE256((t + 2) * 64, cur);  // WAR-safe refill
  }

  // epilogue: split into Q/K/V/G (sections are 1024|256-aligned, block-uniform)
#pragma unroll
  for (int rt = 0; rt < 8; rt++) {
#pragma unroll
    for (int ct = 0; ct < 4; ct++) {
      int grow0 = rowA0 + wm * 128 + rt * 16 + 4 * (lane >> 4);
      int gcol = rowB0 + wn * 64 + ct * 16 + (lane & 15);
      int sec = gcol >> 10;
#pragma unroll
      for (int r = 0; r < 4; r++) {
        int grow = grow0 + r;
        float val = acc[rt][ct][r];
        if (sec == 0)      oQ[(size_t)grow * 1024 + gcol] = f2bf(val);
        else if (sec == 1) oK[(size_t)grow * 1024 + (gcol - 1024)] = f2bf(val);
        else if (sec < 4)  oV[(size_t)grow * 2048 + (gcol - 2048)] = f2bf(val);
        else               oG[(size_t)grow * 2048 + (gcol - 4096)] = f2bf(val);
      }
    }
  }
#undef STAGE256
}

// ---------------------------------------------------------------------------
// out GEMM: 128x128 tile, BK=64, plain block order (512 blocks, 2/CU).
__global__ __launch_bounds__(256) void gemm_out(const short* __restrict__ A,
                                                const short* __restrict__ Bt, int K,
                                                float* __restrict__ oD) {
  __shared__ short ldsA[128 * 64];
  __shared__ short ldsB[128 * 64];
  const int tid = threadIdx.x;
  const int w = tid >> 6, lane = tid & 63;
  const int wm = w >> 1, wn = w & 1;
  const int rowA0 = blockIdx.x * 128, rowB0 = blockIdx.y * 128;
  f32x4 acc[4][4];
#pragma unroll
  for (int m = 0; m < 4; m++)
#pragma unroll
    for (int n = 0; n < 4; n++) acc[m][n] = (f32x4){0.f, 0.f, 0.f, 0.f};

  for (int kt = 0; kt < K; kt += 64) {
#pragma unroll
    for (int i = 0; i < 4; i++) {
      int X = i * 4096 + tid * 16;
      int r = X >> 7;
      int cB = (X & 127) ^ ((r & 7) << 4);
      ASYNC_COPY16((const char*)A + ((size_t)(rowA0 + r) * K + kt) * 2 + cB,
                   (char*)ldsA + X);
      ASYNC_COPY16((const char*)Bt + ((size_t)(rowB0 + r) * K + kt) * 2 + cB,
                   (char*)ldsB + X);
    }
    __syncthreads();
#pragma unroll
    for (int kk = 0; kk < 2; kk++) {
      s16x8 af[4], bfv[4];
#pragma unroll
      for (int mt = 0; mt < 4; mt++) {
        int row = wm * 64 + mt * 16 + (lane & 15);
        int lin = row * 128 + (kk * 32 + 8 * (lane >> 4)) * 2;
        af[mt] = *(const s16x8*)((const char*)ldsA + (lin ^ ((row & 7) << 4)));
      }
#pragma unroll
      for (int nt = 0; nt < 4; nt++) {
        int rowb = wn * 64 + nt * 16 + (lane & 15);
        int lin = rowb * 128 + (kk * 32 + 8 * (lane >> 4)) * 2;
        bfv[nt] = *(const s16x8*)((const char*)ldsB + (lin ^ ((rowb & 7) << 4)));
      }
#pragma unroll
      for (int mt = 0; mt < 4; mt++)
#pragma unroll
        for (int nt = 0; nt < 4; nt++) acc[mt][nt] = mfma16(af[mt], bfv[nt], acc[mt][nt]);
    }
    __syncthreads();
  }
#pragma unroll
  for (int mt = 0; mt < 4; mt++) {
#pragma unroll
    for (int nt = 0; nt < 4; nt++) {
      int grow0 = rowA0 + wm * 64 + mt * 16 + 4 * (lane >> 4);
      int gcol = rowB0 + wn * 64 + nt * 16 + (lane & 15);
#pragma unroll
      for (int r = 0; r < 4; r++) {
        oD[(size_t)(grow0 + r) * 1024 + gcol] = acc[mt][nt][r];
      }
    }
  }
}

// ---------------------------------------------------------------------------
// intra: per-(chunk, bh). 4 waves. Outputs qg, ksT, Adec, o_intra (LDS-staged
// coalesced flush).
__global__ __launch_bounds__(256) void gla_intra(const short* __restrict__ Qb,
                                                 const short* __restrict__ Kb,
                                                 const float* __restrict__ gkp,
                                                 const short* __restrict__ VbT,
                                                 short* __restrict__ qg_g,
                                                 short* __restrict__ ksT_g,
                                                 float* __restrict__ Adec,
                                                 short* __restrict__ obA) {
  __shared__ short smem[64 * 512];     // qgbuf[64*256] | kibuf[64*256]; later o-stage
  __shared__ short scorebuf[64 * 64];
  __shared__ float adecs[256];
  short* qgbuf = smem;
  short* kibuf = smem + 64 * 256;

  const int ch = blockIdx.x, bh = blockIdx.y;
  const int b = bh >> 2, h = bh & 3;
  const int tok0 = b * 2048 + ch * 64;
  const int ltk0 = ch * 64;
  const int tid = threadIdx.x;
  const int col = h * 256 + tid;

  const float scale_ = 0.0625f;
  float cs = 0.f;
#pragma unroll 4
  for (int t = 0; t < 64; t++) {
    size_t ri = (size_t)(tok0 + t) * 1024 + col;
    cs += gkp[ri];
    float qv = bf2f(Qb[ri]);
    float kv = bf2f(Kb[ri]);
    float ep = __expf(cs);
    float en = __expf(-cs);
    short qb = f2bf(qv * ep * scale_);
    short kb = f2bf(kv * en);
    int lin = t * 512 + tid * 2;
    int sw = (t & 7) << 4;
    *(short*)((char*)qgbuf + (lin ^ sw)) = qb;
    *(short*)((char*)kibuf + (lin ^ sw)) = kb;
    qg_g[ri] = qb;
  }
  float elast = __expf(cs);
  Adec[(bh * 32 + ch) * 256 + tid] = elast;
  adecs[tid] = elast;
  __syncthreads();

  const int w = tid >> 6, lane = tid & 63;
  {
    f32x4 sc[4];
#pragma unroll
    for (int nt = 0; nt < 4; nt++) sc[nt] = (f32x4){0.f, 0.f, 0.f, 0.f};
#pragma unroll
    for (int kk = 0; kk < 8; kk++) {
      int row = 16 * w + (lane & 15);
      int lin = row * 512 + (kk * 32 + 8 * (lane >> 4)) * 2;
      s16x8 a = *(const s16x8*)((const char*)qgbuf + (lin ^ ((row & 7) << 4)));
#pragma unroll
      for (int nt = 0; nt < 4; nt++) {
        int tj = nt * 16 + (lane & 15);
        int linb = tj * 512 + (kk * 32 + 8 * (lane >> 4)) * 2;
        s16x8 bb = *(const s16x8*)((const char*)kibuf + (linb ^ ((tj & 7) << 4)));
        sc[nt] = mfma16(a, bb, sc[nt]);
      }
    }
#pragma unroll
    for (int nt = 0; nt < 4; nt++) {
#pragma unroll
      for (int r = 0; r < 4; r++) {
        int ri = 16 * w + 4 * (lane >> 4) + r;
        int cj = nt * 16 + (lane & 15);
        float v = (cj <= ri) ? sc[nt][r] : 0.f;
        int lin = ri * 128 + cj * 2;
        *(short*)((char*)scorebuf + (lin ^ ((ri & 7) << 4))) = f2bf(v);
      }
    }
  }
  __syncthreads();

  size_t ksb = (size_t)(bh * 32 + ch) * 16384;
#pragma unroll
  for (int j = 0; j < 8; j++) {
    int E = j * 2048 + tid * 8;
    int d = E >> 6, t0 = E & 63;
    float el = adecs[d];
    s16x8 v;
#pragma unroll
    for (int r = 0; r < 8; r++) {
      int t = t0 + r;
      short ki = *(const short*)((const char*)kibuf + ((t * 512 + d * 2) ^ ((t & 7) << 4)));
      v[r] = f2bf(bf2f(ki) * el);
    }
    *(s16x8*)(ksT_g + ksb + E) = v;
  }
  __syncthreads();  // smem becomes o-stage [64][512]

  {
    s16x8 a2[2];
#pragma unroll
    for (int kk = 0; kk < 2; kk++) {
      int row = 16 * w + (lane & 15);
      int lin = row * 128 + (kk * 32 + 8 * (lane >> 4)) * 2;
      a2[kk] = *(const s16x8*)((const char*)scorebuf + (lin ^ ((row & 7) << 4)));
    }
    for (int nt = 0; nt < 32; nt++) {
      int e = nt * 16 + (lane & 15);
      f32x4 oacc = (f32x4){0.f, 0.f, 0.f, 0.f};
#pragma unroll
      for (int kk = 0; kk < 2; kk++) {
        const s16x8 bb = *(const s16x8*)(VbT + ((size_t)bh * 512 + e) * 2048 + ltk0 + kk * 32 + 8 * (lane >> 4));
        oacc = mfma16(a2[kk], bb, oacc);
      }
#pragma unroll
      for (int r = 0; r < 4; r++) {
        int ri = 16 * w + 4 * (lane >> 4) + r;
        int lin3 = ri * 1024 + e * 2;
        *(short*)((char*)smem + (lin3 ^ ((ri & 7) << 4))) = f2bf(oacc[r]);
      }
    }
  }
  __syncthreads();
#pragma unroll
  for (int it = 0; it < 16; it++) {
    int row = it * 4 + (tid >> 6);
    int vec = tid & 63;
    int lin = row * 1024 + vec * 16;
    s16x8 v = *(const s16x8*)((const char*)smem + (lin ^ ((row & 7) << 4)));
    *(s16x8*)(obA + (size_t)(tok0 + row) * 2048 + h * 512 + vec * 8) = v;
  }
}

// ---------------------------------------------------------------------------
// state pass: sequential chunks 0..23, materialize boundary states S_8,S_16,S_24.
__global__ __launch_bounds__(256) void gla_state(const short* __restrict__ ksT_g,
                                                 const short* __restrict__ VbT,
                                                 const float* __restrict__ Adec,
                                                 short* __restrict__ Sb) {
  __shared__ short st[32 * 256];
  const int seg = blockIdx.x, bh = blockIdx.y;
  const int tid = threadIdx.x;
  const int w = tid >> 6, lane = tid & 63;

  f32x4 S[4][2];
#pragma unroll
  for (int mt = 0; mt < 4; mt++)
#pragma unroll
    for (int nt = 0; nt < 2; nt++) S[mt][nt] = (f32x4){0.f, 0.f, 0.f, 0.f};

  for (int ch = 0; ch < 24; ch++) {
    const int ltk0 = ch * 64;
#pragma unroll
    for (int mt = 0; mt < 4; mt++) {
      int dkb = 64 * w + mt * 16 + 4 * (lane >> 4);
      f32x4 a = *(const f32x4*)(Adec + (size_t)(bh * 32 + ch) * 256 + dkb);
#pragma unroll
      for (int nt = 0; nt < 2; nt++) {
        S[mt][nt][0] *= a[0]; S[mt][nt][1] *= a[1];
        S[mt][nt][2] *= a[2]; S[mt][nt][3] *= a[3];
      }
    }
    size_t ksb = (size_t)(bh * 32 + ch) * 16384;
#pragma unroll
    for (int kk = 0; kk < 2; kk++) {
      s16x8 ak[4];
#pragma unroll
      for (int mt = 0; mt < 4; mt++) {
        int dk = 64 * w + mt * 16 + (lane & 15);
        ak[mt] = *(const s16x8*)(ksT_g + ksb + (size_t)dk * 64 + kk * 32 + 8 * (lane >> 4));
      }
#pragma unroll
      for (int nt = 0; nt < 2; nt++) {
        int e = seg * 32 + nt * 16 + (lane & 15);
        s16x8 bv = *(const s16x8*)(VbT + ((size_t)bh * 512 + e) * 2048 + ltk0 + kk * 32 + 8 * (lane >> 4));
#pragma unroll
        for (int mt = 0; mt < 4; mt++) S[mt][nt] = mfma16(ak[mt], bv, S[mt][nt]);
      }
    }
    if (ch == 7 || ch == 15 || ch == 23) {
      int g = (ch - 7) >> 3;
      __syncthreads();
#pragma unroll
      for (int mt = 0; mt < 4; mt++) {
#pragma unroll
        for (int nt = 0; nt < 2; nt++) {
          int dv = nt * 16 + (lane & 15);
          int dk0 = 64 * w + mt * 16 + 4 * (lane >> 4);
          s16x4 pk = { f2bf(S[mt][nt][0]), f2bf(S[mt][nt][1]), f2bf(S[mt][nt][2]), f2bf(S[mt][nt][3]) };
          int lin = dv * 512 + dk0 * 2;
          *(s16x4*)((char*)st + (lin ^ ((dv & 7) << 4))) = pk;
        }
      }
      __syncthreads();
      char* dstb = (char*)Sb + (((size_t)(g * 16 + bh) * 512 + seg * 32) * 256) * 2;
#pragma unroll
      for (int it = 0; it < 4; it++) {
        int dv = it * 8 + (tid >> 5);
        int vec = tid & 31;
        int X = dv * 512 + vec * 16;
        s16x8 v = *(const s16x8*)((const char*)st + (X ^ ((dv & 7) << 4)));
        *(s16x8*)(dstb + X) = v;
      }
    }
  }
}

// ---------------------------------------------------------------------------
// scan: 4-way parallel over chunk groups. Grid (seg 16, bh 16, g 4), 8 waves.
__global__ __launch_bounds__(512) void gla_scan(const short* __restrict__ qg_g,
                                                const short* __restrict__ ksT_g,
                                                const short* __restrict__ VbT,
                                                const float* __restrict__ Adec,
                                                const short* __restrict__ Sb,
                                                short* __restrict__ obB) {
  __shared__ short st[32 * 256];
  const int seg = blockIdx.x, bh = blockIdx.y, gz = blockIdx.z;
  const int b = bh >> 2, h = bh & 3;
  const int tid = threadIdx.x;
  const int w = tid >> 6, lane = tid & 63;
  const int tt = w & 3;
  const int dh = w >> 2;
  const int ch0 = gz * 8;

  f32x4 S[2][2];
#pragma unroll
  for (int mt = 0; mt < 2; mt++)
#pragma unroll
    for (int nt = 0; nt < 2; nt++) S[mt][nt] = (f32x4){0.f, 0.f, 0.f, 0.f};

  if (gz > 0) {
    const char* srcb = (const char*)Sb + ((((size_t)(gz - 1) * 16 + bh) * 512 + seg * 32) * 256) * 2;
#pragma unroll
    for (int it = 0; it < 2; it++) {
      int dv = it * 16 + (tid >> 5);
      int vec = tid & 31;
      int X = dv * 512 + vec * 16;
      s16x8 v = *(const s16x8*)(srcb + X);
      *(s16x8*)((char*)st + (X ^ ((dv & 7) << 4))) = v;
    }
    __syncthreads();
#pragma unroll
    for (int mt = 0; mt < 2; mt++) {
#pragma unroll
      for (int nt = 0; nt < 2; nt++) {
        int dv = nt * 16 + (lane & 15);
        int dk0 = 32 * w + mt * 16 + 4 * (lane >> 4);
        int lin = dv * 512 + dk0 * 2;
        s16x4 pk = *(const s16x4*)((const char*)st + (lin ^ ((dv & 7) << 4)));
        S[mt][nt][0] = bf2f(pk[0]); S[mt][nt][1] = bf2f(pk[1]);
        S[mt][nt][2] = bf2f(pk[2]); S[mt][nt][3] = bf2f(pk[3]);
      }
    }
  }

  for (int ch = ch0; ch < ch0 + 8; ch++) {
    const int tok0 = b * 2048 + ch * 64;
    const int ltk0 = ch * 64;

    if (ch != ch0 || gz == 0) {
#pragma unroll
      for (int mt = 0; mt < 2; mt++) {
#pragma unroll
        for (int nt = 0; nt < 2; nt++) {
          int dv = nt * 16 + (lane & 15);
          int dk0 = 32 * w + mt * 16 + 4 * (lane >> 4);
          s16x4 pk = { f2bf(S[mt][nt][0]), f2bf(S[mt][nt][1]), f2bf(S[mt][nt][2]), f2bf(S[mt][nt][3]) };
          int lin = dv * 512 + dk0 * 2;
          *(s16x4*)((char*)st + (lin ^ ((dv & 7) << 4))) = pk;
        }
      }
    }
    __syncthreads();

    {
      s16x8 aq[8];
#pragma unroll
      for (int kk = 0; kk < 8; kk++) {
        int ti = tok0 + 16 * tt + (lane & 15);
        aq[kk] = *(const s16x8*)(qg_g + (size_t)ti * 1024 + h * 256 + kk * 32 + 8 * (lane >> 4));
      }
      f32x4 oi0 = (f32x4){0.f, 0.f, 0.f, 0.f};
      f32x4 oi1 = (f32x4){0.f, 0.f, 0.f, 0.f};
      int dv = 16 * dh + (lane & 15);
      __builtin_amdgcn_s_setprio(1);
#pragma unroll
      for (int kk = 0; kk < 8; kk += 2) {
        int lin0 = dv * 512 + (kk * 32 + 8 * (lane >> 4)) * 2;
        int lin1 = dv * 512 + ((kk + 1) * 32 + 8 * (lane >> 4)) * 2;
        s16x8 b0 = *(const s16x8*)((const char*)st + (lin0 ^ ((dv & 7) << 4)));
        s16x8 b1 = *(const s16x8*)((const char*)st + (lin1 ^ ((dv & 7) << 4)));
        oi0 = mfma16(aq[kk], b0, oi0);
        oi1 = mfma16(aq[kk + 1], b1, oi1);
      }
      __builtin_amdgcn_s_setprio(0);
#pragma unroll
      for (int r = 0; r < 4; r++) {
        int ti = tok0 + 16 * tt + 4 * (lane >> 4) + r;
        obB[(size_t)ti * 2048 + h * 512 + seg * 32 + 16 * dh + (lane & 15)] =
            f2bf(oi0[r] + oi1[r]);
      }
    }

#pragma unroll
    for (int mt = 0; mt < 2; mt++) {
      int dkb = 32 * w + mt * 16 + 4 * (lane >> 4);
      f32x4 a = *(const f32x4*)(Adec + (size_t)(bh * 32 + ch) * 256 + dkb);
#pragma unroll
      for (int nt = 0; nt < 2; nt++) {
        S[mt][nt][0] *= a[0]; S[mt][nt][1] *= a[1];
        S[mt][nt][2] *= a[2]; S[mt][nt][3] *= a[3];
      }
    }

    size_t ksb = (size_t)(bh * 32 + ch) * 16384;
#pragma unroll
    for (int kk = 0; kk < 2; kk++) {
      s16x8 ak[2];
#pragma unroll
      for (int mt = 0; mt < 2; mt++) {
        int dk = 32 * w + mt * 16 + (lane & 15);
        ak[mt] = *(const s16x8*)(ksT_g + ksb + (size_t)dk * 64 + kk * 32 + 8 * (lane >> 4));
      }
#pragma unroll
      for (int nt = 0; nt < 2; nt++) {
        int e = seg * 32 + nt * 16 + (lane & 15);
        s16x8 bv = *(const s16x8*)(VbT + ((size_t)bh * 512 + e) * 2048 + ltk0 + kk * 32 + 8 * (lane >> 4));
#pragma unroll
        for (int mt = 0; mt < 2; mt++) S[mt][nt] = mfma16(ak[mt], bv, S[mt][nt]);
      }
    }
    __syncthreads();
  }
}

// ---------------------------------------------------------------------------
__global__ __launch_bounds__(256) void gate_norm(const short* __restrict__ obA,
                                                 const short* __restrict__ obB,
                                                 const short* __restrict__ Gb,
                                                 const float* __restrict__ gnw,
                                                 short* __restrict__ gated) {
  int row = blockIdx.x, tid = threadIdx.x;
  int lane = tid & 63;
  size_t base = (size_t)row * 2048 + (tid >> 6) * 512 + lane * 8;
  s16x8 av = *(const s16x8*)(obA + base);
  s16x8 bv = *(const s16x8*)(obB + base);
  s16x8 gv = *(const s16x8*)(Gb + base);
  float o[8];
  float ss = 0.f;
#pragma unroll
  for (int j = 0; j < 8; j++) {
    o[j] = bf2f(av[j]) + bf2f(bv[j]);
    ss += o[j] * o[j];
  }
#pragma unroll
  for (int off = 32; off > 0; off >>= 1) ss += __shfl_xor(ss, off);
  float rinv = rsqrtf(ss * (1.0f / 512.0f) + 1e-5f);
  f32x4 w0 = *(const f32x4*)(gnw + lane * 8);
  f32x4 w1 = *(const f32x4*)(gnw + lane * 8 + 4);
  s16x8 out;
#pragma unroll
  for (int j = 0; j < 8; j++) {
    float g = bf2f(gv[j]);
    float sg = g / (1.f + __expf(-g));
    float wj = (j < 4) ? w0[j] : w1[j - 4];
    out[j] = f2bf(o[j] * rinv * wj * sg);
  }
  *(s16x8*)(gated + base) = out;
}

// ---------------------------------------------------------------------------
extern "C" void kernel_launch(void* const* d_in, const int* in_sizes, int n_in,
                              void* d_out, int out_size, void* d_ws, size_t ws_size,
                              hipStream_t stream) {
  const float* hsrc = (const float*)d_in[0];
  const float* Wq   = (const float*)d_in[1];
  const float* Wk   = (const float*)d_in[2];
  const float* Wv   = (const float*)d_in[3];
  const float* Wg   = (const float*)d_in[4];
  const float* Wgk1 = (const float*)d_in[5];
  const float* Wgk2 = (const float*)d_in[6];
  const float* bgk2 = (const float*)d_in[7];
  const float* gnw  = (const float*)d_in[8];
  const float* Wo   = (const float*)d_in[9];
  float* out = (float*)d_out;

  short* hbf = (short*)d_ws;                     // 8192x1024
  short* wT  = hbf + (size_t)8192 * 1024;        // 6144x1024 (Wq|Wk|Wv|Wg)^T
  short* woT = wT + (size_t)6144 * 1024;         // 1024x2048 Wo^T
  short* Qb  = woT + (size_t)1024 * 2048;        // 8192x1024
  short* Kb  = Qb + (size_t)8192 * 1024;
  short* Vb  = Kb + (size_t)8192 * 1024;         // 8192x2048
  short* Gb  = Vb + (size_t)8192 * 2048;         // 8192x2048
  short* VbT = Gb + (size_t)8192 * 2048;         // per-batch V^T
  short* ksT = VbT + (size_t)8192 * 2048;        // [bh*32+ch][256][64]
  short* obA = ksT + (size_t)16 * 32 * 256 * 64; // 8192x2048 o_intra
  float* gkb = (float*)(obA + (size_t)8192 * 2048); // 8192x1024 f32
  float* Adec = gkb + (size_t)8192 * 1024;       // 16*32*256 f32
  short* Sb  = (short*)(Adec + (size_t)16 * 32 * 256); // 3x16x512x256 bf16
  short* qg    = hbf;           // alias: hbf dead after QKVG GEMM
  short* gated = Vb;            // alias: Vb dead after V transpose
  short* obB   = (short*)d_out; // alias: consumed before final GEMM writes

  cvt_f2b_vec<<<8192, 256, 0, stream>>>(hsrc, hbf);
  transpose_weights<<<dim3(32, 32, 5), 256, 0, stream>>>(Wq, Wk, Wv, Wg, Wo, wT, woT);
  gk_fused<<<256, 256, 0, stream>>>(hsrc, Wgk1, Wgk2, bgk2, gkb);
  gemm256<<<dim3(32, 24), 512, 0, stream>>>(hbf, wT, 1024, Qb, Kb, Vb, Gb);
  transpose_s16_batched<<<dim3(32, 32, 4), 256, 0, stream>>>(Vb, VbT, 2048, 2048);
  gla_intra<<<dim3(32, 16), 256, 0, stream>>>(Qb, Kb, gkb, VbT, qg, ksT, Adec, obA);
  gla_state<<<dim3(16, 16), 256, 0, stream>>>(ksT, VbT, Adec, Sb);
  gla_scan<<<dim3(16, 16, 4), 512, 0, stream>>>(qg, ksT, VbT, Adec, Sb, obB);
  gate_norm<<<8192, 256, 0, stream>>>(obA, obB, Gb, gnw, gated);
  gemm_out<<<dim3(64, 8), 256, 0, stream>>>(gated, woT, 2048, out);
}